// Round 4
// baseline (515.919 us; speedup 1.0000x reference)
//
#include <hip/hip_runtime.h>
#include <hip/hip_bf16.h>

#define N_ROWS 8192
#define F_DIM  256

typedef __bf16 bf16x8_t __attribute__((ext_vector_type(8)));
typedef float  f32x4_t  __attribute__((ext_vector_type(4)));
typedef float  f32x2_t  __attribute__((ext_vector_type(2)));

static __device__ __forceinline__ unsigned short f2bf(float x) {
    union { __hip_bfloat16 h; unsigned short u; } c;
    c.h = __float2bfloat16(x);   // RNE
    return c.u;
}
static __device__ __forceinline__ unsigned pk2(float lo, float hi) {
    return (unsigned)f2bf(lo) | ((unsigned)f2bf(hi) << 16);
}

// ---------------------------------------------------------------------------
// K0: W [256][256] fp32 -> bf16, swizzled Ws[kb][n][kc]  (kb=k>>5, kc=k&31)
// so GEMM B-fragment (lane: n=l&15, k=q*8+j) is one contiguous 16B load.
// ---------------------------------------------------------------------------
__global__ __launch_bounds__(256) void wconv_kernel(const float* __restrict__ W,
                                                    unsigned short* __restrict__ Ws) {
    const int kb = blockIdx.x;            // 8 blocks of 32 k-rows
    const int t  = threadIdx.x;
    __shared__ float wt[32][257];
    const int r = t >> 3, g = t & 7;
    const float* src = W + (kb * 32 + r) * F_DIM + g * 32;
#pragma unroll
    for (int i = 0; i < 8; ++i) {
        float4 v = *(const float4*)(src + i * 4);
        wt[r][g * 32 + i * 4 + 0] = v.x;
        wt[r][g * 32 + i * 4 + 1] = v.y;
        wt[r][g * 32 + i * 4 + 2] = v.z;
        wt[r][g * 32 + i * 4 + 3] = v.w;
    }
    __syncthreads();
    unsigned o[16];
#pragma unroll
    for (int k = 0; k < 32; k += 2) o[k >> 1] = pk2(wt[k][t], wt[k + 1][t]);
    uint4* dst = (uint4*)(Ws + kb * 8192 + t * 32);
#pragma unroll
    for (int i = 0; i < 4; ++i) dst[i] = make_uint4(o[4*i], o[4*i+1], o[4*i+2], o[4*i+3]);
}

// ---------------------------------------------------------------------------
// pass1: ONE WAVE PER ROW of A. Streams the 32KB row fully linearly
// (fill-like access: contiguous 2KB per wave-iter, no 32KB-strided pieces),
// accumulates rowsum in-register (butterfly at end -> direct store, no
// atomics / no zeroing), converts to bf16 and scatters into the
// MFMA-fragment-tiled As:
//   tile(b = r>>5, i = k>>6) of 4KB; within tile (shorts):
//   s*1024 + q*256 + mt*128 + m*8 + j   with s=(k>>5)&1, q=(k>>3)&3, j=k&7,
//   m=r&15, mt=(r>>4)&1.
// Each lane's 8 consecutive floats -> one 16B store; a wave's 64 stores land
// inside 8 consecutive tiles (32KB window) -> DRAM-friendly.
// ---------------------------------------------------------------------------
__global__ __launch_bounds__(256) void pass1_kernel(const float* __restrict__ A,
                                                    float* __restrict__ rowsum,
                                                    unsigned short* __restrict__ As) {
    const int r    = (int)((blockIdx.x * 256 + threadIdx.x) >> 6);  // 8192 waves = rows
    const int lane = threadIdx.x & 63;
    const float* src = A + ((size_t)r << 13) + lane * 8;
    const int m = r & 15, mt = (r >> 4) & 1;
    unsigned short* tbase = As + (size_t)(r >> 5) * (128 * 2048) + mt * 128 + m * 8;

    f32x4_t acc0 = {0.f, 0.f, 0.f, 0.f}, acc1 = {0.f, 0.f, 0.f, 0.f};
#pragma unroll 4
    for (int it = 0; it < 16; ++it) {
        const int c0 = it * 512 + lane * 8;        // this lane's first k
        f32x4_t v0 = __builtin_nontemporal_load((f32x4_t*)(src + it * 512));
        f32x4_t v1 = __builtin_nontemporal_load((f32x4_t*)(src + it * 512 + 4));
        acc0 += v0; acc1 += v1;
        uint4 pkd;
        pkd.x = pk2(v0[0], v0[1]); pkd.y = pk2(v0[2], v0[3]);
        pkd.z = pk2(v1[0], v1[1]); pkd.w = pk2(v1[2], v1[3]);
        const size_t soff = (size_t)(c0 >> 6) * 2048
                          + (size_t)((c0 >> 5) & 1) * 1024
                          + (size_t)((c0 >> 3) & 3) * 256;
        *(uint4*)(tbase + soff) = pkd;
    }
    f32x4_t a = acc0 + acc1;
    float s = (a[0] + a[1]) + (a[2] + a[3]);
#pragma unroll
    for (int off = 1; off < 64; off <<= 1) s += __shfl_xor(s, off);
    if (lane == 0) rowsum[r] = s;
}

// ---------------------------------------------------------------------------
// prep2: d = rsqrt(rowsum); dvec; Xs[kb][n][kc] = bf16(d_row * H) swizzled.
// Tiny (12 MB traffic).
// ---------------------------------------------------------------------------
__global__ __launch_bounds__(256) void prep2_kernel(const float* __restrict__ rowsum,
                                                    const float* __restrict__ H,
                                                    float* __restrict__ dvec,
                                                    unsigned short* __restrict__ Xs) {
    const int kb = blockIdx.x;            // 256 blocks, 32 rows each
    const int t  = threadIdx.x;
    __shared__ float dl[32];
    __shared__ float ht[32][257];
    if (t < 32) {
        float d = 1.0f / sqrtf(rowsum[kb * 32 + t]);
        dl[t] = d;
        dvec[kb * 32 + t] = d;
    }
    __syncthreads();
    const int hr = t >> 3, hg = t & 7;    // 32 rows x 8 groups of 32 floats
    const float* hsrc = H + (size_t)(kb * 32 + hr) * F_DIM + hg * 32;
    const float d = dl[hr];
#pragma unroll
    for (int i = 0; i < 8; ++i) {
        float4 v = *(const float4*)(hsrc + i * 4);
        ht[hr][hg * 32 + i * 4 + 0] = v.x * d;
        ht[hr][hg * 32 + i * 4 + 1] = v.y * d;
        ht[hr][hg * 32 + i * 4 + 2] = v.z * d;
        ht[hr][hg * 32 + i * 4 + 3] = v.w * d;
    }
    __syncthreads();
    unsigned o[16];
#pragma unroll
    for (int k = 0; k < 32; k += 2) o[k >> 1] = pk2(ht[k][t], ht[k + 1][t]);
    uint4* dst = (uint4*)(Xs + kb * 8192 + t * 32);
#pragma unroll
    for (int i = 0; i < 4; ++i) dst[i] = make_uint4(o[4*i], o[4*i+1], o[4*i+2], o[4*i+3]);
}

// ---------------------------------------------------------------------------
// gemm1: Y = (A @ Xs) row-scaled by d.  A comes from the PRE-TILED bf16 As:
// block streams consecutive 4KB tiles linearly; every wave loads its own
// fragments straight from global (identical addrs across the 8 waves -> L1).
// NO LDS, NO barriers -> no vmcnt(0) drains; waves drift and cover latency.
// K-split via gridDim.y (2): halves per-block K, 2 blocks/CU, partials in Y.
// ---------------------------------------------------------------------------
template <int KITERS>
__global__ __launch_bounds__(512) void gemm1_kernel(const unsigned short* __restrict__ As,
                                                    const unsigned short* __restrict__ Bs,
                                                    const float* __restrict__ dvec,
                                                    float* __restrict__ Y) {
    const int t    = threadIdx.x;
    const int blk  = blockIdx.x;              // 32-row M band
    const int half = blockIdx.y;              // K-split index
    const int w = t >> 6, l = t & 63;
    const int m = l & 15, q = l >> 4;

    const unsigned short* ap = As + ((size_t)blk * 128 + (size_t)half * KITERS) * 2048
                                  + q * 256 + m * 8;
    const unsigned short* bp = Bs + (size_t)half * KITERS * 16384 + (w * 32 + m) * 32 + q * 8;

    f32x4_t acc[2][2] = {};                   // [mtile][ntile]

    // frag offsets (shorts): a[s*2+mt] = {0,128,1024,1152}; b[s*2+nt] = {0,512,8192,8704}
    uint4 a_cur[4], b_cur[4];
    a_cur[0] = *(const uint4*)(ap);
    a_cur[1] = *(const uint4*)(ap + 128);
    a_cur[2] = *(const uint4*)(ap + 1024);
    a_cur[3] = *(const uint4*)(ap + 1152);
    b_cur[0] = *(const uint4*)(bp);
    b_cur[1] = *(const uint4*)(bp + 512);
    b_cur[2] = *(const uint4*)(bp + 8192);
    b_cur[3] = *(const uint4*)(bp + 8704);

    for (int i = 0; i < KITERS; ++i) {
        uint4 a_nxt[4], b_nxt[4];
        if (i + 1 < KITERS) {
            const unsigned short* an = ap + (size_t)(i + 1) * 2048;
            const unsigned short* bn = bp + (size_t)(i + 1) * 16384;
            a_nxt[0] = *(const uint4*)(an);
            a_nxt[1] = *(const uint4*)(an + 128);
            a_nxt[2] = *(const uint4*)(an + 1024);
            a_nxt[3] = *(const uint4*)(an + 1152);
            b_nxt[0] = *(const uint4*)(bn);
            b_nxt[1] = *(const uint4*)(bn + 512);
            b_nxt[2] = *(const uint4*)(bn + 8192);
            b_nxt[3] = *(const uint4*)(bn + 8704);
        }
#pragma unroll
        for (int s = 0; s < 2; ++s) {
            bf16x8_t af0 = __builtin_bit_cast(bf16x8_t, a_cur[s * 2 + 0]);
            bf16x8_t af1 = __builtin_bit_cast(bf16x8_t, a_cur[s * 2 + 1]);
            bf16x8_t bf0 = __builtin_bit_cast(bf16x8_t, b_cur[s * 2 + 0]);
            bf16x8_t bf1 = __builtin_bit_cast(bf16x8_t, b_cur[s * 2 + 1]);
            acc[0][0] = __builtin_amdgcn_mfma_f32_16x16x32_bf16(af0, bf0, acc[0][0], 0, 0, 0);
            acc[0][1] = __builtin_amdgcn_mfma_f32_16x16x32_bf16(af0, bf1, acc[0][1], 0, 0, 0);
            acc[1][0] = __builtin_amdgcn_mfma_f32_16x16x32_bf16(af1, bf0, acc[1][0], 0, 0, 0);
            acc[1][1] = __builtin_amdgcn_mfma_f32_16x16x32_bf16(af1, bf1, acc[1][1], 0, 0, 0);
        }
#pragma unroll
        for (int k = 0; k < 4; ++k) { a_cur[k] = a_nxt[k]; b_cur[k] = b_nxt[k]; }
    }

    // epilogue: C/D layout row=q*4+r, col=lane&15; this half -> own partial
    float* obase = Y + (size_t)half * ((size_t)N_ROWS * F_DIM);
    const int gcol0 = w * 32 + m;
#pragma unroll
    for (int mt = 0; mt < 2; ++mt) {
#pragma unroll
        for (int r = 0; r < 4; ++r) {
            const int grow = blk * 32 + mt * 16 + q * 4 + r;
            const float ds = dvec[grow];
#pragma unroll
            for (int nt = 0; nt < 2; ++nt) {
                obase[(size_t)grow * F_DIM + gcol0 + nt * 16] = acc[mt][nt][r] * ds;
            }
        }
    }
}

// ---------------------------------------------------------------------------
// gemm2 (R3-proven LDS structure): out = relu((Y1+Y2) @ Wsz).
// Small: K=256, 24 MB traffic, L2-resident inputs.
// ---------------------------------------------------------------------------
template <int KITERS, int ASTRIDE>
__global__ __launch_bounds__(512) void gemm2_kernel(const float* __restrict__ Amat,
                                                    const float* __restrict__ Amat2,
                                                    const unsigned short* __restrict__ Bs,
                                                    float* __restrict__ out) {
    const int t   = threadIdx.x;
    const int blk = blockIdx.x;
    const int w = t >> 6, l = t & 63;
    const int m = l & 15, q = l >> 4;

    __shared__ __align__(16) unsigned short Al[2][1024];

    const int ar = t >> 4, ac = (t & 15) * 2;
    const float* aptr  = Amat  + (size_t)(blk * 32 + ar) * ASTRIDE + ac;
    const float* aptr2 = Amat2 + (size_t)(blk * 32 + ar) * ASTRIDE + ac;
    const int wr_idx = (ac >> 3) * 256 + (ar >> 4) * 128 + (ar & 15) * 8 + (ac & 7);

    const unsigned short* bptr = Bs + (w * 32 + m) * 32 + q * 8;

    f32x4_t acc[2][2] = {};

    f32x2_t a_cur[2]; uint4 b_cur[2][2];
#pragma unroll
    for (int s = 0; s < 2; ++s) {
        f32x2_t a1 = *(const f32x2_t*)(aptr + s * 32);
        f32x2_t a2 = *(const f32x2_t*)(aptr2 + s * 32);
        a_cur[s] = a1 + a2;
        b_cur[s][0] = *(const uint4*)(bptr + s * 8192);
        b_cur[s][1] = *(const uint4*)(bptr + s * 8192 + 512);
    }

    for (int i = 0; i < KITERS; ++i) {
        f32x2_t a_nxt[2]; uint4 b_nxt[2][2];
        if (i + 1 < KITERS) {
            const float* ap  = aptr  + (i + 1) * 64;
            const float* ap2 = aptr2 + (i + 1) * 64;
            const unsigned short* bp = bptr + (size_t)(i + 1) * 16384;
#pragma unroll
            for (int s = 0; s < 2; ++s) {
                f32x2_t a1 = *(const f32x2_t*)(ap + s * 32);
                f32x2_t a2 = *(const f32x2_t*)(ap2 + s * 32);
                a_nxt[s] = a1 + a2;
                b_nxt[s][0] = *(const uint4*)(bp + s * 8192);
                b_nxt[s][1] = *(const uint4*)(bp + s * 8192 + 512);
            }
        }
        const unsigned aw0 = pk2(a_cur[0][0], a_cur[0][1]);
        const unsigned aw1 = pk2(a_cur[1][0], a_cur[1][1]);
        __syncthreads();
        *(unsigned*)&Al[0][wr_idx] = aw0;
        *(unsigned*)&Al[1][wr_idx] = aw1;
        __syncthreads();
#pragma unroll
        for (int s = 0; s < 2; ++s) {
            bf16x8_t af0 = *(const bf16x8_t*)&Al[s][q * 256 + m * 8];
            bf16x8_t af1 = *(const bf16x8_t*)&Al[s][q * 256 + 128 + m * 8];
            bf16x8_t bf0 = __builtin_bit_cast(bf16x8_t, b_cur[s][0]);
            bf16x8_t bf1 = __builtin_bit_cast(bf16x8_t, b_cur[s][1]);
            acc[0][0] = __builtin_amdgcn_mfma_f32_16x16x32_bf16(af0, bf0, acc[0][0], 0, 0, 0);
            acc[0][1] = __builtin_amdgcn_mfma_f32_16x16x32_bf16(af0, bf1, acc[0][1], 0, 0, 0);
            acc[1][0] = __builtin_amdgcn_mfma_f32_16x16x32_bf16(af1, bf0, acc[1][0], 0, 0, 0);
            acc[1][1] = __builtin_amdgcn_mfma_f32_16x16x32_bf16(af1, bf1, acc[1][1], 0, 0, 0);
        }
#pragma unroll
        for (int s = 0; s < 2; ++s) {
            a_cur[s]    = a_nxt[s];
            b_cur[s][0] = b_nxt[s][0];
            b_cur[s][1] = b_nxt[s][1];
        }
    }

    const int gcol0 = w * 32 + m;
#pragma unroll
    for (int mt = 0; mt < 2; ++mt) {
#pragma unroll
        for (int r = 0; r < 4; ++r) {
            const int grow = blk * 32 + mt * 16 + q * 4 + r;
#pragma unroll
            for (int nt = 0; nt < 2; ++nt) {
                out[(size_t)grow * F_DIM + gcol0 + nt * 16] = fmaxf(acc[mt][nt][r], 0.f);
            }
        }
    }
}

// ---------------------------------------------------------------------------
extern "C" void kernel_launch(void* const* d_in, const int* in_sizes, int n_in,
                              void* d_out, int out_size, void* d_ws, size_t ws_size,
                              hipStream_t stream) {
    (void)in_sizes; (void)n_in; (void)out_size; (void)ws_size;
    const float* H = (const float*)d_in[0];
    const float* A = (const float*)d_in[1];
    const float* W = (const float*)d_in[2];
    float* out = (float*)d_out;

    char* ws = (char*)d_ws;
    float*          dvec   = (float*)ws;                                   //  32 KB
    float*          rowsum = (float*)(ws + (32 << 10));                    //  32 KB
    unsigned short* Wsz    = (unsigned short*)(ws + (64 << 10));           // 128 KB
    unsigned short* Xs     = (unsigned short*)(ws + (256 << 10));          //   4 MB
    float*          Y1     = (float*)(ws + (8 << 20));                     //   8 MB
    float*          Y2     = Y1 + (size_t)N_ROWS * F_DIM;                  //   8 MB
    unsigned short* As     = (unsigned short*)(ws + (32 << 20));           // 128 MB

    wconv_kernel<<<dim3(8),    dim3(256), 0, stream>>>(W, Wsz);
    pass1_kernel<<<dim3(2048), dim3(256), 0, stream>>>(A, rowsum, As);
    prep2_kernel<<<dim3(256),  dim3(256), 0, stream>>>(rowsum, H, dvec, Xs);
    gemm1_kernel<64><<<dim3(256, 2), dim3(512), 0, stream>>>(As, Xs, dvec, Y1);
    gemm2_kernel<4, 256><<<dim3(256), dim3(512), 0, stream>>>(Y1, Y2, Wsz, out);
}

// Round 5
// 468.080 us; speedup vs baseline: 1.1022x; 1.1022x over previous
//
#include <hip/hip_runtime.h>
#include <hip/hip_bf16.h>

#define N_ROWS 8192
#define F_DIM  256

typedef __bf16 bf16x8_t __attribute__((ext_vector_type(8)));
typedef float  f32x4_t  __attribute__((ext_vector_type(4)));
typedef float  f32x2_t  __attribute__((ext_vector_type(2)));

static __device__ __forceinline__ unsigned short f2bf(float x) {
    union { __hip_bfloat16 h; unsigned short u; } c;
    c.h = __float2bfloat16(x);   // RNE
    return c.u;
}
static __device__ __forceinline__ unsigned pk2(float lo, float hi) {
    return (unsigned)f2bf(lo) | ((unsigned)f2bf(hi) << 16);
}

// ---------------------------------------------------------------------------
// K0: W [256][256] fp32 -> bf16, swizzled Ws[kb][n][kc]  (kb=k>>5, kc=k&31).
// ---------------------------------------------------------------------------
__global__ __launch_bounds__(256) void wconv_kernel(const float* __restrict__ W,
                                                    unsigned short* __restrict__ Ws) {
    const int kb = blockIdx.x;
    const int t  = threadIdx.x;
    __shared__ float wt[32][257];
    const int r = t >> 3, g = t & 7;
    const float* src = W + (kb * 32 + r) * F_DIM + g * 32;
#pragma unroll
    for (int i = 0; i < 8; ++i) {
        float4 v = *(const float4*)(src + i * 4);
        wt[r][g * 32 + i * 4 + 0] = v.x;
        wt[r][g * 32 + i * 4 + 1] = v.y;
        wt[r][g * 32 + i * 4 + 2] = v.z;
        wt[r][g * 32 + i * 4 + 3] = v.w;
    }
    __syncthreads();
    unsigned o[16];
#pragma unroll
    for (int k = 0; k < 32; k += 2) o[k >> 1] = pk2(wt[k][t], wt[k + 1][t]);
    uint4* dst = (uint4*)(Ws + kb * 8192 + t * 32);
#pragma unroll
    for (int i = 0; i < 4; ++i) dst[i] = make_uint4(o[4*i], o[4*i+1], o[4*i+2], o[4*i+3]);
}

// ---------------------------------------------------------------------------
// prep: block = 32-row band of A (contiguous 1 MB). Reads A fill-like
// (each wave-instruction = 64 lanes x 16 B = 1 KB CONTIGUOUS within one row;
// wave w owns rows 2w,2w+1 -> rowsum accumulates in registers, no atomics).
// Converts to bf16 and scatters into an XOR-swizzled LDS image of the
// MFMA-fragment-tiled layout (quarter = 32 tiles = 128 KB), then writes the
// quarter out to As as a LINEAR 128 KB stream (full-line 1 KB wave stores —
// fixes R4 pass1's 16 B cross-XCD partial-line scatter).
// As logical layout, per band: 128 tiles (kit=k>>6) of 4 KB:
//   byte = sub*2048 + qq*512 + mt*256 + m*16 + j*2
//   with sub=(k>>5)&1, qq=(k>>3)&3, j=k&7, m=row&15, mt=row>>4.
// LDS swizzle: byte ^= ((byte>>9)&7)<<4  (involution; applied on scatter
// write and on write-out read; global As stays linear/unswizzled).
// ---------------------------------------------------------------------------
__global__ __launch_bounds__(1024) void prep_kernel(const float* __restrict__ A,
                                                    float* __restrict__ rowsum,
                                                    unsigned short* __restrict__ As) {
    const int kb   = blockIdx.x;          // 256 bands
    const int t    = threadIdx.x;
    const int w    = t >> 6, lane = t & 63;
    __shared__ __align__(16) char lds[131072];

    const float* Ab = A + ((size_t)kb << 18);     // 32 rows * 8192 floats
    f32x4_t rs0 = {0.f, 0.f, 0.f, 0.f}, rs1 = {0.f, 0.f, 0.f, 0.f};

    for (int q = 0; q < 4; ++q) {                 // 4 column-quarters of 2048
        if (q) __syncthreads();                   // prev write-out done
#pragma unroll
        for (int rr = 0; rr < 2; ++rr) {
            const int r  = w * 2 + rr;
            const int mb = (r >> 4) * 256 + (r & 15) * 16;   // mt*256 + m*16
            const float* rp = Ab + ((size_t)r << 13) + q * 2048;
#pragma unroll
            for (int ch = 0; ch < 8; ++ch) {      // 8 x 1KB contiguous
                f32x4_t v = __builtin_nontemporal_load((const f32x4_t*)(rp + ch * 256 + lane * 4));
                if (rr == 0) rs0 += v; else rs1 += v;
                const int cq  = ch * 256 + lane * 4;         // col within quarter
                int byte = (cq >> 6) * 4096 + ((cq >> 5) & 1) * 2048
                         + ((cq >> 3) & 3) * 512 + mb + ((cq & 7) ? 8 : 0);
                byte ^= ((byte >> 9) & 7) << 4;              // de-conflict swizzle
                uint2 pv; pv.x = pk2(v[0], v[1]); pv.y = pk2(v[2], v[3]);
                *(uint2*)(lds + byte) = pv;
            }
        }
        __syncthreads();
        // write-out: 32 tiles (128 KB) -> As, linear full-line stream
        char* dstb = (char*)As + ((size_t)(kb * 128 + q * 32)) * 4096;
#pragma unroll
        for (int it = 0; it < 8; ++it) {
            const int byte = it * 16384 + t * 16;
            const int sb   = byte ^ (((byte >> 9) & 7) << 4);
            *(uint4*)(dstb + byte) = *(const uint4*)(lds + sb);
        }
    }
    // rowsums: wave-private rows -> butterfly -> store
    {
        float s0 = (rs0[0] + rs0[1]) + (rs0[2] + rs0[3]);
        float s1 = (rs1[0] + rs1[1]) + (rs1[2] + rs1[3]);
#pragma unroll
        for (int off = 1; off < 64; off <<= 1) {
            s0 += __shfl_xor(s0, off);
            s1 += __shfl_xor(s1, off);
        }
        if (lane == 0) {
            rowsum[kb * 32 + w * 2 + 0] = s0;
            rowsum[kb * 32 + w * 2 + 1] = s1;
        }
    }
}

// ---------------------------------------------------------------------------
// prep2: d = rsqrt(rowsum); dvec; Xs[kb][n][kc] = bf16(d_row * H) swizzled.
// ---------------------------------------------------------------------------
__global__ __launch_bounds__(256) void prep2_kernel(const float* __restrict__ rowsum,
                                                    const float* __restrict__ H,
                                                    float* __restrict__ dvec,
                                                    unsigned short* __restrict__ Xs) {
    const int kb = blockIdx.x;
    const int t  = threadIdx.x;
    __shared__ float dl[32];
    __shared__ float ht[32][257];
    if (t < 32) {
        float d = 1.0f / sqrtf(rowsum[kb * 32 + t]);
        dl[t] = d;
        dvec[kb * 32 + t] = d;
    }
    __syncthreads();
    const int hr = t >> 3, hg = t & 7;
    const float* hsrc = H + (size_t)(kb * 32 + hr) * F_DIM + hg * 32;
    const float d = dl[hr];
#pragma unroll
    for (int i = 0; i < 8; ++i) {
        float4 v = *(const float4*)(hsrc + i * 4);
        ht[hr][hg * 32 + i * 4 + 0] = v.x * d;
        ht[hr][hg * 32 + i * 4 + 1] = v.y * d;
        ht[hr][hg * 32 + i * 4 + 2] = v.z * d;
        ht[hr][hg * 32 + i * 4 + 3] = v.w * d;
    }
    __syncthreads();
    unsigned o[16];
#pragma unroll
    for (int k = 0; k < 32; k += 2) o[k >> 1] = pk2(ht[k][t], ht[k + 1][t]);
    uint4* dst = (uint4*)(Xs + kb * 8192 + t * 32);
#pragma unroll
    for (int i = 0; i < 4; ++i) dst[i] = make_uint4(o[4*i], o[4*i+1], o[4*i+2], o[4*i+3]);
}

// ---------------------------------------------------------------------------
// gemm1: Y_half = (A @ Xs) row-scaled, from the PRE-TILED bf16 As.
// Per phase: stage 2 tiles (8 KB = 128 k) with one uint4/thread (1 KB/wave
// contiguous), 2 barriers per 128 k (4x fewer than R3), 1-phase register
// prefetch of the next stage. B-fragments direct from L2 (proven layout).
// K-split via gridDim.y=2 -> 2 blocks/CU.
// ---------------------------------------------------------------------------
template <int PHASES>
__global__ __launch_bounds__(512) void gemm1_kernel(const unsigned short* __restrict__ As,
                                                    const unsigned short* __restrict__ Xs,
                                                    const float* __restrict__ dvec,
                                                    float* __restrict__ Y) {
    const int t    = threadIdx.x;
    const int blk  = blockIdx.x;              // 32-row band
    const int half = blockIdx.y;              // K half
    const int w = t >> 6, l = t & 63;
    const int m = l & 15, q = l >> 4;

    __shared__ __align__(16) char lds[8192];

    const char* asrc = (const char*)As + (size_t)(blk * 128 + half * 64) * 4096 + t * 16;

    f32x4_t acc[2][2] = {};                   // [mtile][ntile]

    uint4 apf = *(const uint4*)asrc;          // phase-0 stage
    for (int p = 0; p < PHASES; ++p) {
        __syncthreads();                      // prior frag reads done
        *(uint4*)&lds[t * 16] = apf;
        __syncthreads();                      // stage visible
        if (p + 1 < PHASES) apf = *(const uint4*)(asrc + (size_t)(p + 1) * 8192);
        const unsigned short* bp = Xs + (size_t)(half * 128 + p * 4) * 8192
                                      + (w * 32 + m) * 32 + q * 8;
#pragma unroll
        for (int ss = 0; ss < 4; ++ss) {      // 4 x k32 sub-steps
            const int fb = (ss >> 1) * 4096 + (ss & 1) * 2048 + q * 512 + m * 16;
            bf16x8_t af0 = *(const bf16x8_t*)&lds[fb];
            bf16x8_t af1 = *(const bf16x8_t*)&lds[fb + 256];
            bf16x8_t bf0 = *(const bf16x8_t*)(bp + ss * 8192);
            bf16x8_t bf1 = *(const bf16x8_t*)(bp + ss * 8192 + 512);
            acc[0][0] = __builtin_amdgcn_mfma_f32_16x16x32_bf16(af0, bf0, acc[0][0], 0, 0, 0);
            acc[0][1] = __builtin_amdgcn_mfma_f32_16x16x32_bf16(af0, bf1, acc[0][1], 0, 0, 0);
            acc[1][0] = __builtin_amdgcn_mfma_f32_16x16x32_bf16(af1, bf0, acc[1][0], 0, 0, 0);
            acc[1][1] = __builtin_amdgcn_mfma_f32_16x16x32_bf16(af1, bf1, acc[1][1], 0, 0, 0);
        }
    }

    // epilogue: C/D row=q*4+r, col=lane&15; this half -> own partial
    float* obase = Y + (size_t)half * ((size_t)N_ROWS * F_DIM);
    const int gcol0 = w * 32 + m;
#pragma unroll
    for (int mt = 0; mt < 2; ++mt) {
#pragma unroll
        for (int r = 0; r < 4; ++r) {
            const int grow = blk * 32 + mt * 16 + q * 4 + r;
            const float ds = dvec[grow];
#pragma unroll
            for (int nt = 0; nt < 2; ++nt) {
                obase[(size_t)grow * F_DIM + gcol0 + nt * 16] = acc[mt][nt][r] * ds;
            }
        }
    }
}

// ---------------------------------------------------------------------------
// gemm2 (R3-proven LDS structure): out = relu((Y1+Y2) @ Wsz). 24 MB traffic.
// ---------------------------------------------------------------------------
template <int KITERS, int ASTRIDE>
__global__ __launch_bounds__(512) void gemm2_kernel(const float* __restrict__ Amat,
                                                    const float* __restrict__ Amat2,
                                                    const unsigned short* __restrict__ Bs,
                                                    float* __restrict__ out) {
    const int t   = threadIdx.x;
    const int blk = blockIdx.x;
    const int w = t >> 6, l = t & 63;
    const int m = l & 15, q = l >> 4;

    __shared__ __align__(16) unsigned short Al[2][1024];

    const int ar = t >> 4, ac = (t & 15) * 2;
    const float* aptr  = Amat  + (size_t)(blk * 32 + ar) * ASTRIDE + ac;
    const float* aptr2 = Amat2 + (size_t)(blk * 32 + ar) * ASTRIDE + ac;
    const int wr_idx = (ac >> 3) * 256 + (ar >> 4) * 128 + (ar & 15) * 8 + (ac & 7);

    const unsigned short* bptr = Bs + (w * 32 + m) * 32 + q * 8;

    f32x4_t acc[2][2] = {};

    f32x2_t a_cur[2]; uint4 b_cur[2][2];
#pragma unroll
    for (int s = 0; s < 2; ++s) {
        f32x2_t a1 = *(const f32x2_t*)(aptr + s * 32);
        f32x2_t a2 = *(const f32x2_t*)(aptr2 + s * 32);
        a_cur[s] = a1 + a2;
        b_cur[s][0] = *(const uint4*)(bptr + s * 8192);
        b_cur[s][1] = *(const uint4*)(bptr + s * 8192 + 512);
    }

    for (int i = 0; i < KITERS; ++i) {
        f32x2_t a_nxt[2]; uint4 b_nxt[2][2];
        if (i + 1 < KITERS) {
            const float* ap  = aptr  + (i + 1) * 64;
            const float* ap2 = aptr2 + (i + 1) * 64;
            const unsigned short* bp = bptr + (size_t)(i + 1) * 16384;
#pragma unroll
            for (int s = 0; s < 2; ++s) {
                f32x2_t a1 = *(const f32x2_t*)(ap + s * 32);
                f32x2_t a2 = *(const f32x2_t*)(ap2 + s * 32);
                a_nxt[s] = a1 + a2;
                b_nxt[s][0] = *(const uint4*)(bp + s * 8192);
                b_nxt[s][1] = *(const uint4*)(bp + s * 8192 + 512);
            }
        }
        const unsigned aw0 = pk2(a_cur[0][0], a_cur[0][1]);
        const unsigned aw1 = pk2(a_cur[1][0], a_cur[1][1]);
        __syncthreads();
        *(unsigned*)&Al[0][wr_idx] = aw0;
        *(unsigned*)&Al[1][wr_idx] = aw1;
        __syncthreads();
#pragma unroll
        for (int s = 0; s < 2; ++s) {
            bf16x8_t af0 = *(const bf16x8_t*)&Al[s][q * 256 + m * 8];
            bf16x8_t af1 = *(const bf16x8_t*)&Al[s][q * 256 + 128 + m * 8];
            bf16x8_t bf0 = __builtin_bit_cast(bf16x8_t, b_cur[s][0]);
            bf16x8_t bf1 = __builtin_bit_cast(bf16x8_t, b_cur[s][1]);
            acc[0][0] = __builtin_amdgcn_mfma_f32_16x16x32_bf16(af0, bf0, acc[0][0], 0, 0, 0);
            acc[0][1] = __builtin_amdgcn_mfma_f32_16x16x32_bf16(af0, bf1, acc[0][1], 0, 0, 0);
            acc[1][0] = __builtin_amdgcn_mfma_f32_16x16x32_bf16(af1, bf0, acc[1][0], 0, 0, 0);
            acc[1][1] = __builtin_amdgcn_mfma_f32_16x16x32_bf16(af1, bf1, acc[1][1], 0, 0, 0);
        }
#pragma unroll
        for (int s = 0; s < 2; ++s) {
            a_cur[s]    = a_nxt[s];
            b_cur[s][0] = b_nxt[s][0];
            b_cur[s][1] = b_nxt[s][1];
        }
    }

    const int gcol0 = w * 32 + m;
#pragma unroll
    for (int mt = 0; mt < 2; ++mt) {
#pragma unroll
        for (int r = 0; r < 4; ++r) {
            const int grow = blk * 32 + mt * 16 + q * 4 + r;
#pragma unroll
            for (int nt = 0; nt < 2; ++nt) {
                out[(size_t)grow * F_DIM + gcol0 + nt * 16] = fmaxf(acc[mt][nt][r], 0.f);
            }
        }
    }
}

// ---------------------------------------------------------------------------
extern "C" void kernel_launch(void* const* d_in, const int* in_sizes, int n_in,
                              void* d_out, int out_size, void* d_ws, size_t ws_size,
                              hipStream_t stream) {
    (void)in_sizes; (void)n_in; (void)out_size; (void)ws_size;
    const float* H = (const float*)d_in[0];
    const float* A = (const float*)d_in[1];
    const float* W = (const float*)d_in[2];
    float* out = (float*)d_out;

    char* ws = (char*)d_ws;
    float*          dvec   = (float*)ws;                                   //  32 KB
    float*          rowsum = (float*)(ws + (32 << 10));                    //  32 KB
    unsigned short* Wsz    = (unsigned short*)(ws + (64 << 10));           // 128 KB
    unsigned short* Xs     = (unsigned short*)(ws + (256 << 10));          //   4 MB
    float*          Y1     = (float*)(ws + (8 << 20));                     //   8 MB
    float*          Y2     = Y1 + (size_t)N_ROWS * F_DIM;                  //   8 MB
    unsigned short* As     = (unsigned short*)(ws + (32 << 20));           // 128 MB

    wconv_kernel<<<dim3(8),   dim3(256),  0, stream>>>(W, Wsz);
    prep_kernel <<<dim3(256), dim3(1024), 0, stream>>>(A, rowsum, As);
    prep2_kernel<<<dim3(256), dim3(256),  0, stream>>>(rowsum, H, dvec, Xs);
    gemm1_kernel<32><<<dim3(256, 2), dim3(512), 0, stream>>>(As, Xs, dvec, Y1);
    gemm2_kernel<4, 256><<<dim3(256), dim3(512), 0, stream>>>(Y1, Y2, Wsz, out);
}